// Round 2
// baseline (280.109 us; speedup 1.0000x reference)
//
#include <hip/hip_runtime.h>
#include <stdint.h>

typedef float          f32x4  __attribute__((ext_vector_type(4)));
typedef __bf16         bf16x8 __attribute__((ext_vector_type(8)));
typedef unsigned short u16x4  __attribute__((ext_vector_type(4)));
typedef unsigned short u16x8  __attribute__((ext_vector_type(8)));

#define LOG2E 1.44269504f

__device__ __forceinline__ float bf2f(unsigned short u) {
    union { uint32_t i; float f; } v; v.i = ((uint32_t)u) << 16; return v.f;
}
__device__ __forceinline__ unsigned short f2bf(float f) {
    union { float f; uint32_t i; } v; v.f = f;
    uint32_t x = v.i;
    return (unsigned short)((x + 0x7FFFu + ((x >> 16) & 1u)) >> 16);
}
__device__ __forceinline__ f32x4 mfma16(bf16x8 a, bf16x8 b, f32x4 c) {
    return __builtin_amdgcn_mfma_f32_16x16x32_bf16(a, b, c, 0, 0, 0);
}

// ---------------------------------------------------------------------------
// Kernel 1: QKV GEMM.  C[o][n] = sum_c Wqkv[o][c] * X[b][c][n],  o in [0,768)
// M=768 (o), N=4096 (n), K=256 (c).  128x128 tiles, BK=64, 4 waves (2x2).
// Inputs f32 (converted to bf16 during LDS staging).
// Writes Q,K in [bh][n][d] layout (bf16), V in [bh][d][m] layout (bf16).
// ---------------------------------------------------------------------------
__global__ __launch_bounds__(256) void qkv_gemm(
    const float* __restrict__ x, const float* __restrict__ wqkv,
    unsigned short* __restrict__ Qb, unsigned short* __restrict__ Kb,
    unsigned short* __restrict__ Vb) {
    const int mt = blockIdx.x;          // 0..5
    const int nt = blockIdx.y;          // 0..31
    const int b  = blockIdx.z;          // 0..3
    const int o0 = mt * 128, n0 = nt * 128;
    __shared__ unsigned short Wt[128 * 72];   // [o][c] pad 72
    __shared__ unsigned short Xt[128 * 72];   // [n][c] pad 72 (transposed)
    const int t = threadIdx.x;
    const int lane = t & 63, w = t >> 6;
    const int wr = w >> 1, wc = w & 1;
    const int l15 = lane & 15, g = lane >> 4;

    f32x4 acc[4][4];
    const f32x4 zero = {0.f, 0.f, 0.f, 0.f};
    for (int i = 0; i < 4; i++) for (int j = 0; j < 4; j++) acc[i][j] = zero;

    for (int k0 = 0; k0 < 256; k0 += 64) {
        // stage W tile: f32 -> bf16, [o][c]
        {
            const int row = t >> 3, col = (t & 7) * 8;
            #pragma unroll
            for (int r = 0; r < 4; r++) {
                const float* p = wqkv + (size_t)(o0 + row + r * 32) * 256 + k0 + col;
                f32x4 v0 = *(const f32x4*)p;
                f32x4 v1 = *(const f32x4*)(p + 4);
                u16x8 o8 = { f2bf(v0[0]), f2bf(v0[1]), f2bf(v0[2]), f2bf(v0[3]),
                             f2bf(v1[0]), f2bf(v1[1]), f2bf(v1[2]), f2bf(v1[3]) };
                *(u16x8*)(&Wt[(row + r * 32) * 72 + col]) = o8;
            }
        }
        // stage X^T tile: read x[c][n] coalesced over n, write [n][c] bf16
        {
            const int cl = t >> 4, nl = (t & 15) * 8;
            #pragma unroll
            for (int r = 0; r < 4; r++) {
                const int c = k0 + cl + r * 16;
                const float* p = x + (size_t)(b * 512 + c) * 4096 + n0 + nl;
                f32x4 v0 = *(const f32x4*)p;
                f32x4 v1 = *(const f32x4*)(p + 4);
                #pragma unroll
                for (int j = 0; j < 4; j++) Xt[(nl + j) * 72 + cl + r * 16] = f2bf(v0[j]);
                #pragma unroll
                for (int j = 0; j < 4; j++) Xt[(nl + 4 + j) * 72 + cl + r * 16] = f2bf(v1[j]);
            }
        }
        __syncthreads();
        #pragma unroll
        for (int kk = 0; kk < 2; kk++) {
            bf16x8 af[4], bfr[4];
            #pragma unroll
            for (int i = 0; i < 4; i++)
                af[i] = *(const bf16x8*)(&Wt[(wr * 64 + i * 16 + l15) * 72 + kk * 32 + g * 8]);
            #pragma unroll
            for (int j = 0; j < 4; j++)
                bfr[j] = *(const bf16x8*)(&Xt[(wc * 64 + j * 16 + l15) * 72 + kk * 32 + g * 8]);
            #pragma unroll
            for (int i = 0; i < 4; i++)
                #pragma unroll
                for (int j = 0; j < 4; j++)
                    acc[i][j] = mfma16(af[i], bfr[j], acc[i][j]);
        }
        __syncthreads();
    }

    // epilogue: D frag: col n = l15, rows o = base + g*4 + r
    #pragma unroll
    for (int i = 0; i < 4; i++) {
        const int o = o0 + wr * 64 + i * 16 + g * 4;
        #pragma unroll
        for (int j = 0; j < 4; j++) {
            const int n = n0 + wc * 64 + j * 16 + l15;
            f32x4 a = acc[i][j];
            u16x4 pv = { f2bf(a[0]), f2bf(a[1]), f2bf(a[2]), f2bf(a[3]) };
            if (o < 256) {
                const int h = o >> 6, d = o & 63;
                *(u16x4*)(&Qb[(((size_t)(b * 4 + h)) * 4096 + n) * 64 + d]) = pv;
            } else if (o < 512) {
                const int oo = o - 256; const int h = oo >> 6, d = oo & 63;
                *(u16x4*)(&Kb[(((size_t)(b * 4 + h)) * 4096 + n) * 64 + d]) = pv;
            } else {
                const int oo = o - 512; const int h = oo >> 6, d = oo & 63;
                const size_t base = (((size_t)(b * 4 + h)) * 64 + d) * 4096 + n;
                Vb[base] = pv[0]; Vb[base + 4096] = pv[1];
                Vb[base + 8192] = pv[2]; Vb[base + 12288] = pv[3];
            }
        }
    }
}

// ---------------------------------------------------------------------------
// Kernel 2: flash attention.  Per (b,h): S^T = K·Q^T (scaled), online softmax
// over m (rows of S^T), O^T[d][n] += V·P^T.  QBLK=128 (4 waves x 32 rows),
// KVBLK=64.  All operands bf16 (workspace).  Writes att[b][n][h*64+d] bf16.
// ---------------------------------------------------------------------------
__global__ __launch_bounds__(256) void flash_attn(
    const unsigned short* __restrict__ Qb, const unsigned short* __restrict__ Kb,
    const unsigned short* __restrict__ Vb, unsigned short* __restrict__ att) {
    const int nb = blockIdx.x;          // 0..31
    const int bh = blockIdx.y;          // 0..15
    const int b = bh >> 2, h = bh & 3;
    const int n0 = nb * 128;
    __shared__ unsigned short Kt[64 * 72];        // [m][d]
    __shared__ unsigned short Vt[64 * 72];        // [d][m]
    __shared__ unsigned short Pt[4 * 32 * 72];    // per-wave [n][m]
    const int t = threadIdx.x, lane = t & 63, w = t >> 6;
    const int l15 = lane & 15, g = lane >> 4;
    unsigned short* Pw = &Pt[w * 32 * 72];

    // Q fragments in registers, pre-scaled by 1/8 (exact in bf16)
    bf16x8 qf[2][2];
    #pragma unroll
    for (int ntl = 0; ntl < 2; ntl++) {
        const int n = n0 + w * 32 + ntl * 16 + l15;
        #pragma unroll
        for (int kk = 0; kk < 2; kk++) {
            u16x8 v = *(const u16x8*)(Qb + (((size_t)bh) * 4096 + n) * 64 + kk * 32 + g * 8);
            #pragma unroll
            for (int j = 0; j < 8; j++)
                v[j] = (unsigned short)(__float_as_uint(bf2f(v[j]) * 0.125f) >> 16);
            qf[ntl][kk] = __builtin_bit_cast(bf16x8, v);
        }
    }

    float mstate[2] = {-INFINITY, -INFINITY};
    float lstate[2] = {0.f, 0.f};
    f32x4 of[4][2];
    const f32x4 zero = {0.f, 0.f, 0.f, 0.f};
    #pragma unroll
    for (int dt = 0; dt < 4; dt++) for (int ntl = 0; ntl < 2; ntl++) of[dt][ntl] = zero;

    for (int it = 0; it < 64; it++) {
        const int m0 = it * 64;
        // stage K [m][d] and V [d][m] tiles (both linear bf16 copies)
        {
            const int row = t >> 3, col = (t & 7) * 8;
            #pragma unroll
            for (int r = 0; r < 2; r++) {
                u16x8 kv = *(const u16x8*)(Kb + (((size_t)bh) * 4096 + m0 + row + r * 32) * 64 + col);
                *(u16x8*)(&Kt[(row + r * 32) * 72 + col]) = kv;
                u16x8 vv = *(const u16x8*)(Vb + (((size_t)bh) * 64 + row + r * 32) * 4096 + m0 + col);
                *(u16x8*)(&Vt[(row + r * 32) * 72 + col]) = vv;
            }
        }
        __syncthreads();

        // S^T[m][n] = sum_d K[m][d] Q^T[d][n]   (already scaled via Q)
        f32x4 st[4][2];
        #pragma unroll
        for (int mt = 0; mt < 4; mt++) {
            bf16x8 ka0 = *(const bf16x8*)(&Kt[(mt * 16 + l15) * 72 + g * 8]);
            bf16x8 ka1 = *(const bf16x8*)(&Kt[(mt * 16 + l15) * 72 + 32 + g * 8]);
            #pragma unroll
            for (int ntl = 0; ntl < 2; ntl++) {
                f32x4 s = zero;
                s = mfma16(ka0, qf[ntl][0], s);
                s = mfma16(ka1, qf[ntl][1], s);
                st[mt][ntl] = s;
            }
        }

        // online softmax over m (within-lane 16 values + xor16/32)
        #pragma unroll
        for (int ntl = 0; ntl < 2; ntl++) {
            float tm = -INFINITY;
            #pragma unroll
            for (int mt = 0; mt < 4; mt++)
                #pragma unroll
                for (int r = 0; r < 4; r++) tm = fmaxf(tm, st[mt][ntl][r]);
            tm = fmaxf(tm, __shfl_xor(tm, 16, 64));
            tm = fmaxf(tm, __shfl_xor(tm, 32, 64));
            const float mnew = fmaxf(mstate[ntl], tm);
            const float alpha = exp2f((mstate[ntl] - mnew) * LOG2E);
            float rs = 0.f;
            #pragma unroll
            for (int mt = 0; mt < 4; mt++) {
                f32x4 p;
                #pragma unroll
                for (int r = 0; r < 4; r++) {
                    p[r] = exp2f((st[mt][ntl][r] - mnew) * LOG2E);
                    rs += p[r];
                }
                st[mt][ntl] = p;
            }
            rs += __shfl_xor(rs, 16, 64);
            rs += __shfl_xor(rs, 32, 64);
            lstate[ntl] = lstate[ntl] * alpha + rs;
            mstate[ntl] = mnew;
            #pragma unroll
            for (int dt = 0; dt < 4; dt++)
                #pragma unroll
                for (int r = 0; r < 4; r++) of[dt][ntl][r] *= alpha;
            // write P^T to per-wave LDS [n][m]: lane writes 4 consecutive m
            #pragma unroll
            for (int mt = 0; mt < 4; mt++) {
                f32x4 p = st[mt][ntl];
                u16x4 pv = { f2bf(p[0]), f2bf(p[1]), f2bf(p[2]), f2bf(p[3]) };
                *(u16x4*)(&Pw[(ntl * 16 + l15) * 72 + mt * 16 + g * 4]) = pv;
            }
        }

        // O^T[d][n] += V[d][m] · P^T[m][n]
        #pragma unroll
        for (int dt = 0; dt < 4; dt++) {
            bf16x8 va0 = *(const bf16x8*)(&Vt[(dt * 16 + l15) * 72 + g * 8]);
            bf16x8 va1 = *(const bf16x8*)(&Vt[(dt * 16 + l15) * 72 + 32 + g * 8]);
            #pragma unroll
            for (int ntl = 0; ntl < 2; ntl++) {
                bf16x8 pb0 = *(const bf16x8*)(&Pw[(ntl * 16 + l15) * 72 + g * 8]);
                bf16x8 pb1 = *(const bf16x8*)(&Pw[(ntl * 16 + l15) * 72 + 32 + g * 8]);
                of[dt][ntl] = mfma16(va0, pb0, of[dt][ntl]);
                of[dt][ntl] = mfma16(va1, pb1, of[dt][ntl]);
            }
        }
        __syncthreads();
    }

    // epilogue: att[b][n][h*64 + d] = O / l
    #pragma unroll
    for (int ntl = 0; ntl < 2; ntl++) {
        const float inv = 1.f / lstate[ntl];
        const int n = n0 + w * 32 + ntl * 16 + l15;
        #pragma unroll
        for (int dt = 0; dt < 4; dt++) {
            f32x4 a = of[dt][ntl];
            u16x4 pv = { f2bf(a[0] * inv), f2bf(a[1] * inv), f2bf(a[2] * inv), f2bf(a[3] * inv) };
            *(u16x4*)(&att[(((size_t)b) * 4096 + n) * 256 + h * 64 + dt * 16 + g * 4]) = pv;
        }
    }
}

// ---------------------------------------------------------------------------
// Kernel 3: proj GEMM.  proj[b][o][n] (f32) = sum_c Wp[o][c] * att[b][n][c]
// M=256, N=4096, K=256.  Wp is f32 (converted in staging); att is bf16.
// ---------------------------------------------------------------------------
__global__ __launch_bounds__(256) void proj_gemm(
    const unsigned short* __restrict__ att, const float* __restrict__ wproj,
    float* __restrict__ proj) {
    const int mt = blockIdx.x;          // 0..1
    const int nt = blockIdx.y;          // 0..31
    const int b  = blockIdx.z;          // 0..3
    const int o0 = mt * 128, n0 = nt * 128;
    __shared__ unsigned short Wt[128 * 72];
    __shared__ unsigned short Bt[128 * 72];
    const int t = threadIdx.x;
    const int lane = t & 63, w = t >> 6;
    const int wr = w >> 1, wc = w & 1;
    const int l15 = lane & 15, g = lane >> 4;

    f32x4 acc[4][4];
    const f32x4 zero = {0.f, 0.f, 0.f, 0.f};
    for (int i = 0; i < 4; i++) for (int j = 0; j < 4; j++) acc[i][j] = zero;

    for (int k0 = 0; k0 < 256; k0 += 64) {
        const int row = t >> 3, col = (t & 7) * 8;
        #pragma unroll
        for (int r = 0; r < 4; r++) {
            const float* p = wproj + (size_t)(o0 + row + r * 32) * 256 + k0 + col;
            f32x4 v0 = *(const f32x4*)p;
            f32x4 v1 = *(const f32x4*)(p + 4);
            u16x8 o8 = { f2bf(v0[0]), f2bf(v0[1]), f2bf(v0[2]), f2bf(v0[3]),
                         f2bf(v1[0]), f2bf(v1[1]), f2bf(v1[2]), f2bf(v1[3]) };
            *(u16x8*)(&Wt[(row + r * 32) * 72 + col]) = o8;
            u16x8 a = *(const u16x8*)(att + (((size_t)b) * 4096 + n0 + row + r * 32) * 256 + k0 + col);
            *(u16x8*)(&Bt[(row + r * 32) * 72 + col]) = a;
        }
        __syncthreads();
        #pragma unroll
        for (int kk = 0; kk < 2; kk++) {
            bf16x8 af[4], bfr[4];
            #pragma unroll
            for (int i = 0; i < 4; i++)
                af[i] = *(const bf16x8*)(&Wt[(wr * 64 + i * 16 + l15) * 72 + kk * 32 + g * 8]);
            #pragma unroll
            for (int j = 0; j < 4; j++)
                bfr[j] = *(const bf16x8*)(&Bt[(wc * 64 + j * 16 + l15) * 72 + kk * 32 + g * 8]);
            #pragma unroll
            for (int i = 0; i < 4; i++)
                #pragma unroll
                for (int j = 0; j < 4; j++)
                    acc[i][j] = mfma16(af[i], bfr[j], acc[i][j]);
        }
        __syncthreads();
    }

    #pragma unroll
    for (int i = 0; i < 4; i++) {
        const int o = o0 + wr * 64 + i * 16 + g * 4;
        #pragma unroll
        for (int j = 0; j < 4; j++) {
            const int n = n0 + wc * 64 + j * 16 + l15;
            f32x4 a = acc[i][j];
            #pragma unroll
            for (int r = 0; r < 4; r++)
                proj[((size_t)(b * 256 + o + r)) * 4096 + n] = a[r];
        }
    }
}

// ---------------------------------------------------------------------------
// Kernel 4: BN stats.  One block per channel o: mean/rstd over (b,n) = 16384.
// ---------------------------------------------------------------------------
__global__ __launch_bounds__(256) void bn_stats(const float* __restrict__ proj,
                                                float* __restrict__ stats) {
    const int o = blockIdx.x, t = threadIdx.x;
    const int lane = t & 63, w = t >> 6;
    float s = 0.f, sq = 0.f;
    for (int i = 0; i < 64; i++) {
        const int idx = t + i * 256;
        const int bb = idx >> 12, n = idx & 4095;
        const float v = proj[((size_t)(bb * 256 + o)) * 4096 + n];
        s += v; sq += v * v;
    }
    #pragma unroll
    for (int m = 1; m < 64; m <<= 1) {
        s  += __shfl_xor(s, m, 64);
        sq += __shfl_xor(sq, m, 64);
    }
    __shared__ float red[8];
    if (lane == 0) { red[w] = s; red[4 + w] = sq; }
    __syncthreads();
    if (t == 0) {
        const float S = red[0] + red[1] + red[2] + red[3];
        const float Q = red[4] + red[5] + red[6] + red[7];
        const float mean = S * (1.f / 16384.f);
        const float var = Q * (1.f / 16384.f) - mean * mean;
        stats[o] = mean;
        stats[256 + o] = rsqrtf(var + 1e-5f);
    }
}

// ---------------------------------------------------------------------------
// Kernel 5: BN apply + gamma/beta + concat skip.  All f32 I/O.
// ---------------------------------------------------------------------------
__global__ __launch_bounds__(256) void bn_apply(
    const float* __restrict__ proj, const float* __restrict__ stats,
    const float* __restrict__ gamma, const float* __restrict__ beta,
    const float* __restrict__ x, float* __restrict__ out) {
    const size_t idx8 = ((size_t)blockIdx.x * 256 + threadIdx.x) * 8;
    const int n  = (int)(idx8 & 4095);
    const int ch = (int)((idx8 >> 12) & 511);
    const int b  = (int)(idx8 >> 21);
    if (ch < 256) {
        const float mean = stats[ch], rstd = stats[256 + ch];
        const float sc = gamma[ch] * rstd;
        const float sh = beta[ch] - mean * sc;
        const float* p = proj + (((size_t)(b * 256 + ch)) << 12) + n;
        f32x4 v0 = *(const f32x4*)p;
        f32x4 v1 = *(const f32x4*)(p + 4);
        f32x4 o0, o1;
        #pragma unroll
        for (int j = 0; j < 4; j++) { o0[j] = v0[j] * sc + sh; o1[j] = v1[j] * sc + sh; }
        *(f32x4*)(out + idx8) = o0;
        *(f32x4*)(out + idx8 + 4) = o1;
    } else {
        *(f32x4*)(out + idx8)     = *(const f32x4*)(x + idx8);
        *(f32x4*)(out + idx8 + 4) = *(const f32x4*)(x + idx8 + 4);
    }
}

// ---------------------------------------------------------------------------
extern "C" void kernel_launch(void* const* d_in, const int* in_sizes, int n_in,
                              void* d_out, int out_size, void* d_ws, size_t ws_size,
                              hipStream_t stream) {
    const float* x     = (const float*)d_in[0];
    const float* wqkv  = (const float*)d_in[1];
    const float* wproj = (const float*)d_in[2];
    const float* gamma = (const float*)d_in[3];
    const float* beta  = (const float*)d_in[4];
    float* out = (float*)d_out;

    char* ws = (char*)d_ws;
    unsigned short* Qb  = (unsigned short*)(ws);                    // 8 MB
    unsigned short* Kb  = (unsigned short*)(ws + (8u  << 20));      // 8 MB
    unsigned short* Vb  = (unsigned short*)(ws + (16u << 20));      // 8 MB
    unsigned short* att = (unsigned short*)(ws + (24u << 20));      // 8 MB
    float*          proj = (float*)(ws + (32u << 20));              // 16 MB
    float*          stats = (float*)(ws + (48u << 20));             // 2 KB

    qkv_gemm <<<dim3(6, 32, 4), 256, 0, stream>>>(x, wqkv, Qb, Kb, Vb);
    flash_attn<<<dim3(32, 16),   256, 0, stream>>>(Qb, Kb, Vb, att);
    proj_gemm<<<dim3(2, 32, 4),  256, 0, stream>>>(att, wproj, proj);
    bn_stats <<<256,             256, 0, stream>>>(proj, stats);
    bn_apply <<<4096,            256, 0, stream>>>(proj, stats, gamma, beta, x, out);
}

// Round 3
// 220.989 us; speedup vs baseline: 1.2675x; 1.2675x over previous
//
#include <hip/hip_runtime.h>
#include <stdint.h>

typedef float          f32x4  __attribute__((ext_vector_type(4)));
typedef __bf16         bf16x8 __attribute__((ext_vector_type(8)));
typedef unsigned short u16x4  __attribute__((ext_vector_type(4)));
typedef unsigned short u16x8  __attribute__((ext_vector_type(8)));

__device__ __forceinline__ unsigned short bfc(float f) {
    return __builtin_bit_cast(unsigned short, (__bf16)f);
}
__device__ __forceinline__ f32x4 mfma16(bf16x8 a, bf16x8 b, f32x4 c) {
    return __builtin_amdgcn_mfma_f32_16x16x32_bf16(a, b, c, 0, 0, 0);
}
// async global->LDS, 16B per lane; LDS dest = wave-uniform base + lane*16
__device__ __forceinline__ void async16(const unsigned short* g, unsigned short* l) {
    __builtin_amdgcn_global_load_lds(
        (const __attribute__((address_space(1))) void*)g,
        (__attribute__((address_space(3))) void*)l, 16, 0, 0);
}

#define QSC 0.18033688f   /* 0.125 * log2(e): S produced in exp2 domain */

// ---------------------------------------------------------------------------
// Kernel 1: QKV GEMM.  C[o][n] = sum_c Wqkv[o][c] * X[b][c][n],  o in [0,768)
// f32 inputs -> bf16 LDS staging.  Q written pre-scaled by 0.125*log2e.
// Q,K layout [bh][n][d]; V layout [bh][d][m].
// ---------------------------------------------------------------------------
__global__ __launch_bounds__(256) void qkv_gemm(
    const float* __restrict__ x, const float* __restrict__ wqkv,
    unsigned short* __restrict__ Qb, unsigned short* __restrict__ Kb,
    unsigned short* __restrict__ Vb) {
    const int mt = blockIdx.x;          // 0..5
    const int nt = blockIdx.y;          // 0..31
    const int b  = blockIdx.z;          // 0..3
    const int o0 = mt * 128, n0 = nt * 128;
    __shared__ __align__(16) unsigned short Wt[128 * 72];   // [o][c] pad 72
    __shared__ __align__(16) unsigned short Xt[128 * 72];   // [n][c] pad 72
    const int t = threadIdx.x;
    const int lane = t & 63, w = t >> 6;
    const int wr = w >> 1, wc = w & 1;
    const int l15 = lane & 15, g = lane >> 4;

    f32x4 acc[4][4];
    const f32x4 zero = {0.f, 0.f, 0.f, 0.f};
    for (int i = 0; i < 4; i++) for (int j = 0; j < 4; j++) acc[i][j] = zero;

    for (int k0 = 0; k0 < 256; k0 += 64) {
        {
            const int row = t >> 3, col = (t & 7) * 8;
            #pragma unroll
            for (int r = 0; r < 4; r++) {
                const float* p = wqkv + (size_t)(o0 + row + r * 32) * 256 + k0 + col;
                f32x4 v0 = *(const f32x4*)p;
                f32x4 v1 = *(const f32x4*)(p + 4);
                u16x8 o8 = { bfc(v0[0]), bfc(v0[1]), bfc(v0[2]), bfc(v0[3]),
                             bfc(v1[0]), bfc(v1[1]), bfc(v1[2]), bfc(v1[3]) };
                *(u16x8*)(&Wt[(row + r * 32) * 72 + col]) = o8;
            }
        }
        {
            const int cl = t >> 4, nl = (t & 15) * 8;
            #pragma unroll
            for (int r = 0; r < 4; r++) {
                const int c = k0 + cl + r * 16;
                const float* p = x + (size_t)(b * 512 + c) * 4096 + n0 + nl;
                f32x4 v0 = *(const f32x4*)p;
                f32x4 v1 = *(const f32x4*)(p + 4);
                #pragma unroll
                for (int j = 0; j < 4; j++) Xt[(nl + j) * 72 + cl + r * 16] = bfc(v0[j]);
                #pragma unroll
                for (int j = 0; j < 4; j++) Xt[(nl + 4 + j) * 72 + cl + r * 16] = bfc(v1[j]);
            }
        }
        __syncthreads();
        #pragma unroll
        for (int kk = 0; kk < 2; kk++) {
            bf16x8 af[4], bfr[4];
            #pragma unroll
            for (int i = 0; i < 4; i++)
                af[i] = *(const bf16x8*)(&Wt[(wr * 64 + i * 16 + l15) * 72 + kk * 32 + g * 8]);
            #pragma unroll
            for (int j = 0; j < 4; j++)
                bfr[j] = *(const bf16x8*)(&Xt[(wc * 64 + j * 16 + l15) * 72 + kk * 32 + g * 8]);
            #pragma unroll
            for (int i = 0; i < 4; i++)
                #pragma unroll
                for (int j = 0; j < 4; j++)
                    acc[i][j] = mfma16(af[i], bfr[j], acc[i][j]);
        }
        __syncthreads();
    }

    #pragma unroll
    for (int i = 0; i < 4; i++) {
        const int o = o0 + wr * 64 + i * 16 + g * 4;
        #pragma unroll
        for (int j = 0; j < 4; j++) {
            const int n = n0 + wc * 64 + j * 16 + l15;
            f32x4 a = acc[i][j];
            if (o < 256) {
                u16x4 pv = { bfc(a[0] * QSC), bfc(a[1] * QSC), bfc(a[2] * QSC), bfc(a[3] * QSC) };
                const int h = o >> 6, d = o & 63;
                *(u16x4*)(&Qb[(((size_t)(b * 4 + h)) * 4096 + n) * 64 + d]) = pv;
            } else if (o < 512) {
                u16x4 pv = { bfc(a[0]), bfc(a[1]), bfc(a[2]), bfc(a[3]) };
                const int oo = o - 256; const int h = oo >> 6, d = oo & 63;
                *(u16x4*)(&Kb[(((size_t)(b * 4 + h)) * 4096 + n) * 64 + d]) = pv;
            } else {
                const int oo = o - 512; const int h = oo >> 6, d = oo & 63;
                const size_t base = (((size_t)(b * 4 + h)) * 64 + d) * 4096 + n;
                Vb[base] = bfc(a[0]); Vb[base + 4096] = bfc(a[1]);
                Vb[base + 8192] = bfc(a[2]); Vb[base + 12288] = bfc(a[3]);
            }
        }
    }
}

// ---------------------------------------------------------------------------
// Kernel 2: flash attention, 16 q-rows/wave, 4 waves (QBLK=64), KVBLK=64.
// K,V double-buffered linear [64][64] LDS staged via global_load_lds with
// XOR swizzle (elem ^= (row&7)<<3) applied on reads; global source addresses
// pre-swizzled (both-sides rule).  S in exp2 domain (Q pre-scaled).
// Online softmax with defer-max (THR=8).  One barrier per iteration.
// ---------------------------------------------------------------------------
__global__ __launch_bounds__(256) void flash_attn(
    const unsigned short* __restrict__ Qb, const unsigned short* __restrict__ Kb,
    const unsigned short* __restrict__ Vb, unsigned short* __restrict__ att) {
    __shared__ __align__(16) unsigned short Kt[2][64 * 64];
    __shared__ __align__(16) unsigned short Vt[2][64 * 64];
    __shared__ __align__(16) unsigned short Pt[4][16 * 64];

    // XCD-aware swizzle: 1024 blocks, 8 XCDs -> each XCD owns 2 consecutive bh
    const int flat = blockIdx.y * 64 + blockIdx.x;
    const int nf = (flat & 7) * 128 + (flat >> 3);
    const int bh = nf >> 6;
    const int nb = nf & 63;

    const int t = threadIdx.x, lane = t & 63, w = t >> 6;
    const int l15 = lane & 15, g = lane >> 4;
    const int xo = (l15 & 7) << 3;              // element-space XOR for reads
    const int c0 = (g * 8) ^ xo, c1 = c0 ^ 32;

    // staging source addresses (pre-swizzled, stay within each 128B row)
    const int rb = lane >> 3;                                  // 0..7
    const int cbe = ((lane & 7) ^ rb) << 3;                    // element col offset
    const unsigned short* kg0; const unsigned short* kg1;
    const unsigned short* vg0; const unsigned short* vg1;
    {
        const int row0 = w * 8 + rb, row1 = 32 + w * 8 + rb;
        kg0 = Kb + ((size_t)bh * 4096 + row0) * 64 + cbe;
        kg1 = Kb + ((size_t)bh * 4096 + row1) * 64 + cbe;
        vg0 = Vb + ((size_t)(bh * 64 + row0)) * 4096 + cbe;
        vg1 = Vb + ((size_t)(bh * 64 + row1)) * 4096 + cbe;
    }
    unsigned short* Kt0 = &Kt[0][0];
    unsigned short* Vt0 = &Vt[0][0];
    unsigned short* Pw  = &Pt[w][0];

    auto stage = [&](int buf, int it2) {
        const size_t ko = (size_t)it2 * 4096;   // K advances 64 rows
        const size_t vo = (size_t)it2 * 64;     // V advances 64 columns
        unsigned short* dk = Kt0 + buf * 4096 + w * 512;
        unsigned short* dv = Vt0 + buf * 4096 + w * 512;
        async16(kg0 + ko, dk);
        async16(kg1 + ko, dk + 2048);
        async16(vg0 + vo, dv);
        async16(vg1 + vo, dv + 2048);
    };

    // Q fragment (already scaled into exp2 domain at QKV epilogue)
    const int n = nb * 64 + w * 16 + l15;
    const unsigned short* qp = Qb + ((size_t)bh * 4096 + n) * 64;
    const bf16x8 qf0 = *(const bf16x8*)(qp + g * 8);
    const bf16x8 qf1 = *(const bf16x8*)(qp + 32 + g * 8);

    f32x4 of[4];
    const f32x4 zero = {0.f, 0.f, 0.f, 0.f};
    of[0] = of[1] = of[2] = of[3] = zero;
    float m_run = -1e30f, l_run = 0.f;

    stage(0, 0);
    __syncthreads();

    int cur = 0;
    for (int it = 0; it < 64; ++it) {
        if (it < 63) stage(cur ^ 1, it + 1);    // async into other buffer

        // S^T[m][n] (exp2 domain): m = mt*16+g*4+r, n = l15
        f32x4 st[4];
        #pragma unroll
        for (int mt = 0; mt < 4; ++mt) {
            const unsigned short* kp = Kt0 + cur * 4096 + (mt * 16 + l15) * 64;
            bf16x8 ka0 = *(const bf16x8*)(kp + c0);
            bf16x8 ka1 = *(const bf16x8*)(kp + c1);
            f32x4 s = mfma16(ka0, qf0, zero);
            st[mt] = mfma16(ka1, qf1, s);
        }

        // tile column-max (reduce 16 in-lane + xor16 + xor32)
        float tm = st[0][0];
        #pragma unroll
        for (int mt = 0; mt < 4; ++mt)
            #pragma unroll
            for (int r = 0; r < 4; ++r) tm = fmaxf(tm, st[mt][r]);
        tm = fmaxf(tm, __shfl_xor(tm, 16, 64));
        tm = fmaxf(tm, __shfl_xor(tm, 32, 64));

        // defer-max: only rescale when some column grew its max by > 8
        if (!__all(tm <= m_run + 8.f)) {
            const float mnew = fmaxf(m_run, tm);
            const float alpha = exp2f(m_run - mnew);
            #pragma unroll
            for (int dt = 0; dt < 4; ++dt)
                #pragma unroll
                for (int r = 0; r < 4; ++r) of[dt][r] *= alpha;
            l_run *= alpha;
            m_run = mnew;
        }

        float rs = 0.f;
        #pragma unroll
        for (int mt = 0; mt < 4; ++mt) {
            f32x4 p;
            #pragma unroll
            for (int r = 0; r < 4; ++r) { p[r] = exp2f(st[mt][r] - m_run); rs += p[r]; }
            st[mt] = p;
        }
        rs += __shfl_xor(rs, 16, 64);
        rs += __shfl_xor(rs, 32, 64);
        l_run += rs;

        // P^T -> per-wave LDS [n=l15][m], swizzled
        #pragma unroll
        for (int mt = 0; mt < 4; ++mt) {
            u16x4 pv = { bfc(st[mt][0]), bfc(st[mt][1]), bfc(st[mt][2]), bfc(st[mt][3]) };
            *(u16x4*)(&Pw[l15 * 64 + ((mt * 16 + g * 4) ^ xo)]) = pv;
        }

        // O^T[d][n] += V[d][m] · P^T[m][n]
        bf16x8 pb0 = *(const bf16x8*)(&Pw[l15 * 64 + c0]);
        bf16x8 pb1 = *(const bf16x8*)(&Pw[l15 * 64 + c1]);
        #pragma unroll
        for (int dt = 0; dt < 4; ++dt) {
            const unsigned short* vp = Vt0 + cur * 4096 + (dt * 16 + l15) * 64;
            bf16x8 va0 = *(const bf16x8*)(vp + c0);
            bf16x8 va1 = *(const bf16x8*)(vp + c1);
            f32x4 o = mfma16(va0, pb0, of[dt]);
            of[dt] = mfma16(va1, pb1, o);
        }
        __syncthreads();        // drains prefetch (vmcnt0) + guards buffer swap
        cur ^= 1;
    }

    // epilogue: att[b][n][h*64 + d] = O / l
    const int b = bh >> 2, h = bh & 3;
    const float inv = 1.f / l_run;
    #pragma unroll
    for (int dt = 0; dt < 4; ++dt) {
        u16x4 pv = { bfc(of[dt][0] * inv), bfc(of[dt][1] * inv),
                     bfc(of[dt][2] * inv), bfc(of[dt][3] * inv) };
        *(u16x4*)(&att[(((size_t)b) * 4096 + n) * 256 + h * 64 + dt * 16 + g * 4]) = pv;
    }
}

// ---------------------------------------------------------------------------
// Kernel 3: proj GEMM.  proj[b][o][n] (f32) = sum_c Wp[o][c] * att[b][n][c]
// ---------------------------------------------------------------------------
__global__ __launch_bounds__(256) void proj_gemm(
    const unsigned short* __restrict__ att, const float* __restrict__ wproj,
    float* __restrict__ proj) {
    const int mt = blockIdx.x;          // 0..1
    const int nt = blockIdx.y;          // 0..31
    const int b  = blockIdx.z;          // 0..3
    const int o0 = mt * 128, n0 = nt * 128;
    __shared__ __align__(16) unsigned short Wt[128 * 72];
    __shared__ __align__(16) unsigned short Bt[128 * 72];
    const int t = threadIdx.x;
    const int lane = t & 63, w = t >> 6;
    const int wr = w >> 1, wc = w & 1;
    const int l15 = lane & 15, g = lane >> 4;

    f32x4 acc[4][4];
    const f32x4 zero = {0.f, 0.f, 0.f, 0.f};
    for (int i = 0; i < 4; i++) for (int j = 0; j < 4; j++) acc[i][j] = zero;

    for (int k0 = 0; k0 < 256; k0 += 64) {
        const int row = t >> 3, col = (t & 7) * 8;
        #pragma unroll
        for (int r = 0; r < 4; r++) {
            const float* p = wproj + (size_t)(o0 + row + r * 32) * 256 + k0 + col;
            f32x4 v0 = *(const f32x4*)p;
            f32x4 v1 = *(const f32x4*)(p + 4);
            u16x8 o8 = { bfc(v0[0]), bfc(v0[1]), bfc(v0[2]), bfc(v0[3]),
                         bfc(v1[0]), bfc(v1[1]), bfc(v1[2]), bfc(v1[3]) };
            *(u16x8*)(&Wt[(row + r * 32) * 72 + col]) = o8;
            u16x8 a = *(const u16x8*)(att + (((size_t)b) * 4096 + n0 + row + r * 32) * 256 + k0 + col);
            *(u16x8*)(&Bt[(row + r * 32) * 72 + col]) = a;
        }
        __syncthreads();
        #pragma unroll
        for (int kk = 0; kk < 2; kk++) {
            bf16x8 af[4], bfr[4];
            #pragma unroll
            for (int i = 0; i < 4; i++)
                af[i] = *(const bf16x8*)(&Wt[(wr * 64 + i * 16 + l15) * 72 + kk * 32 + g * 8]);
            #pragma unroll
            for (int j = 0; j < 4; j++)
                bfr[j] = *(const bf16x8*)(&Bt[(wc * 64 + j * 16 + l15) * 72 + kk * 32 + g * 8]);
            #pragma unroll
            for (int i = 0; i < 4; i++)
                #pragma unroll
                for (int j = 0; j < 4; j++)
                    acc[i][j] = mfma16(af[i], bfr[j], acc[i][j]);
        }
        __syncthreads();
    }

    #pragma unroll
    for (int i = 0; i < 4; i++) {
        const int o = o0 + wr * 64 + i * 16 + g * 4;
        #pragma unroll
        for (int j = 0; j < 4; j++) {
            const int n = n0 + wc * 64 + j * 16 + l15;
            f32x4 a = acc[i][j];
            #pragma unroll
            for (int r = 0; r < 4; r++)
                proj[((size_t)(b * 256 + o + r)) * 4096 + n] = a[r];
        }
    }
}

// ---------------------------------------------------------------------------
// Kernel 4: BN stats.  One block per channel o: mean/rstd over (b,n) = 16384.
// ---------------------------------------------------------------------------
__global__ __launch_bounds__(256) void bn_stats(const float* __restrict__ proj,
                                                float* __restrict__ stats) {
    const int o = blockIdx.x, t = threadIdx.x;
    const int lane = t & 63, w = t >> 6;
    float s = 0.f, sq = 0.f;
    for (int i = 0; i < 64; i++) {
        const int idx = t + i * 256;
        const int bb = idx >> 12, n = idx & 4095;
        const float v = proj[((size_t)(bb * 256 + o)) * 4096 + n];
        s += v; sq += v * v;
    }
    #pragma unroll
    for (int m = 1; m < 64; m <<= 1) {
        s  += __shfl_xor(s, m, 64);
        sq += __shfl_xor(sq, m, 64);
    }
    __shared__ float red[8];
    if (lane == 0) { red[w] = s; red[4 + w] = sq; }
    __syncthreads();
    if (t == 0) {
        const float S = red[0] + red[1] + red[2] + red[3];
        const float Q = red[4] + red[5] + red[6] + red[7];
        const float mean = S * (1.f / 16384.f);
        const float var = Q * (1.f / 16384.f) - mean * mean;
        stats[o] = mean;
        stats[256 + o] = rsqrtf(var + 1e-5f);
    }
}

// ---------------------------------------------------------------------------
// Kernel 5: BN apply + gamma/beta + concat skip.  All f32 I/O.
// ---------------------------------------------------------------------------
__global__ __launch_bounds__(256) void bn_apply(
    const float* __restrict__ proj, const float* __restrict__ stats,
    const float* __restrict__ gamma, const float* __restrict__ beta,
    const float* __restrict__ x, float* __restrict__ out) {
    const size_t idx8 = ((size_t)blockIdx.x * 256 + threadIdx.x) * 8;
    const int n  = (int)(idx8 & 4095);
    const int ch = (int)((idx8 >> 12) & 511);
    const int b  = (int)(idx8 >> 21);
    if (ch < 256) {
        const float mean = stats[ch], rstd = stats[256 + ch];
        const float sc = gamma[ch] * rstd;
        const float sh = beta[ch] - mean * sc;
        const float* p = proj + (((size_t)(b * 256 + ch)) << 12) + n;
        f32x4 v0 = *(const f32x4*)p;
        f32x4 v1 = *(const f32x4*)(p + 4);
        f32x4 o0, o1;
        #pragma unroll
        for (int j = 0; j < 4; j++) { o0[j] = v0[j] * sc + sh; o1[j] = v1[j] * sc + sh; }
        *(f32x4*)(out + idx8) = o0;
        *(f32x4*)(out + idx8 + 4) = o1;
    } else {
        *(f32x4*)(out + idx8)     = *(const f32x4*)(x + idx8);
        *(f32x4*)(out + idx8 + 4) = *(const f32x4*)(x + idx8 + 4);
    }
}

// ---------------------------------------------------------------------------
extern "C" void kernel_launch(void* const* d_in, const int* in_sizes, int n_in,
                              void* d_out, int out_size, void* d_ws, size_t ws_size,
                              hipStream_t stream) {
    const float* x     = (const float*)d_in[0];
    const float* wqkv  = (const float*)d_in[1];
    const float* wproj = (const float*)d_in[2];
    const float* gamma = (const float*)d_in[3];
    const float* beta  = (const float*)d_in[4];
    float* out = (float*)d_out;

    char* ws = (char*)d_ws;
    unsigned short* Qb  = (unsigned short*)(ws);                    // 8 MB
    unsigned short* Kb  = (unsigned short*)(ws + (8u  << 20));      // 8 MB
    unsigned short* Vb  = (unsigned short*)(ws + (16u << 20));      // 8 MB
    unsigned short* att = (unsigned short*)(ws + (24u << 20));      // 8 MB
    float*          proj = (float*)(ws + (32u << 20));              // 16 MB
    float*          stats = (float*)(ws + (48u << 20));             // 2 KB

    qkv_gemm <<<dim3(6, 32, 4), 256, 0, stream>>>(x, wqkv, Qb, Kb, Vb);
    flash_attn<<<dim3(64, 16),   256, 0, stream>>>(Qb, Kb, Vb, att);
    proj_gemm<<<dim3(2, 32, 4),  256, 0, stream>>>(att, wproj, proj);
    bn_stats <<<256,             256, 0, stream>>>(proj, stats);
    bn_apply <<<4096,            256, 0, stream>>>(proj, stats, gamma, beta, x, out);
}

// Round 4
// 170.073 us; speedup vs baseline: 1.6470x; 1.2994x over previous
//
#include <hip/hip_runtime.h>
#include <stdint.h>

typedef float          f32x4  __attribute__((ext_vector_type(4)));
typedef __bf16         bf16x8 __attribute__((ext_vector_type(8)));
typedef unsigned short u16x4  __attribute__((ext_vector_type(4)));
typedef unsigned short u16x8  __attribute__((ext_vector_type(8)));

__device__ __forceinline__ unsigned short bfc(float f) {
    return __builtin_bit_cast(unsigned short, (__bf16)f);
}
__device__ __forceinline__ f32x4 mfma16(bf16x8 a, bf16x8 b, f32x4 c) {
    return __builtin_amdgcn_mfma_f32_16x16x32_bf16(a, b, c, 0, 0, 0);
}
// async global->LDS, 16B per lane; LDS dest = wave-uniform base + lane*16
__device__ __forceinline__ void async16(const unsigned short* g, unsigned short* l) {
    __builtin_amdgcn_global_load_lds(
        (const __attribute__((address_space(1))) void*)g,
        (__attribute__((address_space(3))) void*)l, 16, 0, 0);
}

#define QSC 0.18033688f   /* 0.125 * log2(e): S produced in exp2 domain */

// ---------------------------------------------------------------------------
// Kernel 1: QKV GEMM.  C[o][n] = sum_c Wqkv[o][c] * X[b][c][n],  o in [0,768)
// f32 inputs -> bf16 LDS staging.  Q written pre-scaled by 0.125*log2e.
// Q,K layout [bh][n][d]; V layout [bh][d][m].
// ---------------------------------------------------------------------------
__global__ __launch_bounds__(256) void qkv_gemm(
    const float* __restrict__ x, const float* __restrict__ wqkv,
    unsigned short* __restrict__ Qb, unsigned short* __restrict__ Kb,
    unsigned short* __restrict__ Vb) {
    const int mt = blockIdx.x;          // 0..5
    const int nt = blockIdx.y;          // 0..31
    const int b  = blockIdx.z;          // 0..3
    const int o0 = mt * 128, n0 = nt * 128;
    __shared__ __align__(16) unsigned short Wt[128 * 72];   // [o][c] pad 72
    __shared__ __align__(16) unsigned short Xt[128 * 72];   // [n][c] pad 72
    const int t = threadIdx.x;
    const int lane = t & 63, w = t >> 6;
    const int wr = w >> 1, wc = w & 1;
    const int l15 = lane & 15, g = lane >> 4;

    f32x4 acc[4][4];
    const f32x4 zero = {0.f, 0.f, 0.f, 0.f};
    for (int i = 0; i < 4; i++) for (int j = 0; j < 4; j++) acc[i][j] = zero;

    for (int k0 = 0; k0 < 256; k0 += 64) {
        {
            const int row = t >> 3, col = (t & 7) * 8;
            #pragma unroll
            for (int r = 0; r < 4; r++) {
                const float* p = wqkv + (size_t)(o0 + row + r * 32) * 256 + k0 + col;
                f32x4 v0 = *(const f32x4*)p;
                f32x4 v1 = *(const f32x4*)(p + 4);
                u16x8 o8 = { bfc(v0[0]), bfc(v0[1]), bfc(v0[2]), bfc(v0[3]),
                             bfc(v1[0]), bfc(v1[1]), bfc(v1[2]), bfc(v1[3]) };
                *(u16x8*)(&Wt[(row + r * 32) * 72 + col]) = o8;
            }
        }
        {
            const int cl = t >> 4, nl = (t & 15) * 8;
            #pragma unroll
            for (int r = 0; r < 4; r++) {
                const int c = k0 + cl + r * 16;
                const float* p = x + (size_t)(b * 512 + c) * 4096 + n0 + nl;
                f32x4 v0 = *(const f32x4*)p;
                f32x4 v1 = *(const f32x4*)(p + 4);
                #pragma unroll
                for (int j = 0; j < 4; j++) Xt[(nl + j) * 72 + cl + r * 16] = bfc(v0[j]);
                #pragma unroll
                for (int j = 0; j < 4; j++) Xt[(nl + 4 + j) * 72 + cl + r * 16] = bfc(v1[j]);
            }
        }
        __syncthreads();
        #pragma unroll
        for (int kk = 0; kk < 2; kk++) {
            bf16x8 af[4], bfr[4];
            #pragma unroll
            for (int i = 0; i < 4; i++)
                af[i] = *(const bf16x8*)(&Wt[(wr * 64 + i * 16 + l15) * 72 + kk * 32 + g * 8]);
            #pragma unroll
            for (int j = 0; j < 4; j++)
                bfr[j] = *(const bf16x8*)(&Xt[(wc * 64 + j * 16 + l15) * 72 + kk * 32 + g * 8]);
            #pragma unroll
            for (int i = 0; i < 4; i++)
                #pragma unroll
                for (int j = 0; j < 4; j++)
                    acc[i][j] = mfma16(af[i], bfr[j], acc[i][j]);
        }
        __syncthreads();
    }

    #pragma unroll
    for (int i = 0; i < 4; i++) {
        const int o = o0 + wr * 64 + i * 16 + g * 4;
        #pragma unroll
        for (int j = 0; j < 4; j++) {
            const int n = n0 + wc * 64 + j * 16 + l15;
            f32x4 a = acc[i][j];
            if (o < 256) {
                u16x4 pv = { bfc(a[0] * QSC), bfc(a[1] * QSC), bfc(a[2] * QSC), bfc(a[3] * QSC) };
                const int h = o >> 6, d = o & 63;
                *(u16x4*)(&Qb[(((size_t)(b * 4 + h)) * 4096 + n) * 64 + d]) = pv;
            } else if (o < 512) {
                u16x4 pv = { bfc(a[0]), bfc(a[1]), bfc(a[2]), bfc(a[3]) };
                const int oo = o - 256; const int h = oo >> 6, d = oo & 63;
                *(u16x4*)(&Kb[(((size_t)(b * 4 + h)) * 4096 + n) * 64 + d]) = pv;
            } else {
                const int oo = o - 512; const int h = oo >> 6, d = oo & 63;
                const size_t base = (((size_t)(b * 4 + h)) * 64 + d) * 4096 + n;
                Vb[base] = bfc(a[0]); Vb[base + 4096] = bfc(a[1]);
                Vb[base + 8192] = bfc(a[2]); Vb[base + 12288] = bfc(a[3]);
            }
        }
    }
}

// ---------------------------------------------------------------------------
// Kernel 2: flash attention.  8 waves/block (512 thr), QBLK=128 (16 rows/wave),
// KVBLK=64.  K,V double-buffered linear [64][64] LDS via global_load_lds,
// XOR swizzle (elem ^= (row&7)<<3) on reads, pre-swizzled global sources.
// S in exp2 domain.  Defer-max (THR=8) + per-lane deferred l-reduction.
// ---------------------------------------------------------------------------
__global__ __launch_bounds__(512) void flash_attn(
    const unsigned short* __restrict__ Qb, const unsigned short* __restrict__ Kb,
    const unsigned short* __restrict__ Vb, unsigned short* __restrict__ att) {
    __shared__ __align__(16) unsigned short Kt[2][64 * 64];   // 16 KB
    __shared__ __align__(16) unsigned short Vt[2][64 * 64];   // 16 KB
    __shared__ __align__(16) unsigned short Pt[8][16 * 64];   // 16 KB

    // XCD-aware swizzle: 512 blocks, 8 XCDs, 64 blocks/XCD (2 heads per XCD)
    const int flat = blockIdx.y * 32 + blockIdx.x;
    const int swz = (flat & 7) * 64 + (flat >> 3);
    const int bh = swz >> 5;            // 0..15
    const int nb = swz & 31;            // 0..31  (q-tile of 128)

    const int t = threadIdx.x, lane = t & 63, w = t >> 6;    // w = 0..7
    const int l15 = lane & 15, g = lane >> 4;
    const int xo = (l15 & 7) << 3;              // element-space XOR for reads
    const int c0 = (g * 8) ^ xo, c1 = c0 ^ 32;

    // staging source addresses (pre-swizzled, within each 128B row)
    const int rb = lane >> 3;                                  // 0..7
    const int cbe = ((lane & 7) ^ rb) << 3;                    // element col offset
    const int row0 = w * 8 + rb;                               // 0..63 across 8 waves
    const unsigned short* kg0 = Kb + ((size_t)bh * 4096 + row0) * 64 + cbe;
    const unsigned short* vg0 = Vb + ((size_t)(bh * 64 + row0)) * 4096 + cbe;

    unsigned short* Kt0 = &Kt[0][0];
    unsigned short* Vt0 = &Vt[0][0];
    unsigned short* Pw  = &Pt[w][0];

    auto stage = [&](int buf, int it2) {
        async16(kg0 + (size_t)it2 * 4096, Kt0 + buf * 4096 + w * 512);
        async16(vg0 + (size_t)it2 * 64,   Vt0 + buf * 4096 + w * 512);
    };

    // Q fragment (already scaled into exp2 domain at QKV epilogue)
    const int n = nb * 128 + w * 16 + l15;
    const unsigned short* qp = Qb + ((size_t)bh * 4096 + n) * 64;
    const bf16x8 qf0 = *(const bf16x8*)(qp + g * 8);
    const bf16x8 qf1 = *(const bf16x8*)(qp + 32 + g * 8);

    f32x4 of[4];
    const f32x4 zero = {0.f, 0.f, 0.f, 0.f};
    of[0] = of[1] = of[2] = of[3] = zero;
    float m_run = -1e30f, l_run = 0.f;          // l_run: per-lane partial

    stage(0, 0);
    __syncthreads();

    int cur = 0;
    for (int it = 0; it < 64; ++it) {
        if (it < 63) stage(cur ^ 1, it + 1);    // async into other buffer

        // S^T[m][n] (exp2 domain): m = mt*16+g*4+r, n = l15
        f32x4 st[4];
        __builtin_amdgcn_s_setprio(1);
        #pragma unroll
        for (int mt = 0; mt < 4; ++mt) {
            const unsigned short* kp = Kt0 + cur * 4096 + (mt * 16 + l15) * 64;
            bf16x8 ka0 = *(const bf16x8*)(kp + c0);
            bf16x8 ka1 = *(const bf16x8*)(kp + c1);
            f32x4 s = mfma16(ka0, qf0, zero);
            st[mt] = mfma16(ka1, qf1, s);
        }
        __builtin_amdgcn_s_setprio(0);

        // tile column-max: max3-friendly tree + xor16 + xor32
        float a0 = fmaxf(fmaxf(st[0][0], st[0][1]), fmaxf(st[0][2], st[0][3]));
        float a1 = fmaxf(fmaxf(st[1][0], st[1][1]), fmaxf(st[1][2], st[1][3]));
        float a2 = fmaxf(fmaxf(st[2][0], st[2][1]), fmaxf(st[2][2], st[2][3]));
        float a3 = fmaxf(fmaxf(st[3][0], st[3][1]), fmaxf(st[3][2], st[3][3]));
        float tm = fmaxf(fmaxf(a0, a1), fmaxf(a2, a3));
        tm = fmaxf(tm, __shfl_xor(tm, 16, 64));
        tm = fmaxf(tm, __shfl_xor(tm, 32, 64));

        // defer-max: only rescale when some column grew its max by > 8
        if (!__all(tm <= m_run + 8.f)) {
            const float mnew = fmaxf(m_run, tm);
            const float alpha = __builtin_amdgcn_exp2f(m_run - mnew);
            #pragma unroll
            for (int dt = 0; dt < 4; ++dt)
                #pragma unroll
                for (int r = 0; r < 4; ++r) of[dt][r] *= alpha;
            l_run *= alpha;
            m_run = mnew;
        }

        // P = exp2(S - m); l accumulates per-lane (reduced once at epilogue)
        #pragma unroll
        for (int mt = 0; mt < 4; ++mt) {
            f32x4 p;
            #pragma unroll
            for (int r = 0; r < 4; ++r) {
                p[r] = __builtin_amdgcn_exp2f(st[mt][r] - m_run);
                l_run += p[r];
            }
            st[mt] = p;
        }

        // P^T -> per-wave LDS [n=l15][m], swizzled
        #pragma unroll
        for (int mt = 0; mt < 4; ++mt) {
            u16x4 pv = { bfc(st[mt][0]), bfc(st[mt][1]), bfc(st[mt][2]), bfc(st[mt][3]) };
            *(u16x4*)(&Pw[l15 * 64 + ((mt * 16 + g * 4) ^ xo)]) = pv;
        }

        // O^T[d][n] += V[d][m] · P^T[m][n]
        bf16x8 pb0 = *(const bf16x8*)(&Pw[l15 * 64 + c0]);
        bf16x8 pb1 = *(const bf16x8*)(&Pw[l15 * 64 + c1]);
        __builtin_amdgcn_s_setprio(1);
        #pragma unroll
        for (int dt = 0; dt < 4; ++dt) {
            const unsigned short* vp = Vt0 + cur * 4096 + (dt * 16 + l15) * 64;
            bf16x8 va0 = *(const bf16x8*)(vp + c0);
            bf16x8 va1 = *(const bf16x8*)(vp + c1);
            f32x4 o = mfma16(va0, pb0, of[dt]);
            of[dt] = mfma16(va1, pb1, o);
        }
        __builtin_amdgcn_s_setprio(0);
        __syncthreads();        // drains prefetch + guards buffer swap
        cur ^= 1;
    }

    // epilogue: reduce per-lane l partials, then att[b][n][h*64+d] = O / l
    l_run += __shfl_xor(l_run, 16, 64);
    l_run += __shfl_xor(l_run, 32, 64);
    const int b = bh >> 2, h = bh & 3;
    const float inv = 1.f / l_run;
    #pragma unroll
    for (int dt = 0; dt < 4; ++dt) {
        u16x4 pv = { bfc(of[dt][0] * inv), bfc(of[dt][1] * inv),
                     bfc(of[dt][2] * inv), bfc(of[dt][3] * inv) };
        *(u16x4*)(&att[(((size_t)b) * 4096 + n) * 256 + h * 64 + dt * 16 + g * 4]) = pv;
    }
}

// ---------------------------------------------------------------------------
// Kernel 3: proj GEMM.  proj[b][o][n] (f32) = sum_c Wp[o][c] * att[b][n][c]
// ---------------------------------------------------------------------------
__global__ __launch_bounds__(256) void proj_gemm(
    const unsigned short* __restrict__ att, const float* __restrict__ wproj,
    float* __restrict__ proj) {
    const int mt = blockIdx.x;          // 0..1
    const int nt = blockIdx.y;          // 0..31
    const int b  = blockIdx.z;          // 0..3
    const int o0 = mt * 128, n0 = nt * 128;
    __shared__ __align__(16) unsigned short Wt[128 * 72];
    __shared__ __align__(16) unsigned short Bt[128 * 72];
    const int t = threadIdx.x;
    const int lane = t & 63, w = t >> 6;
    const int wr = w >> 1, wc = w & 1;
    const int l15 = lane & 15, g = lane >> 4;

    f32x4 acc[4][4];
    const f32x4 zero = {0.f, 0.f, 0.f, 0.f};
    for (int i = 0; i < 4; i++) for (int j = 0; j < 4; j++) acc[i][j] = zero;

    for (int k0 = 0; k0 < 256; k0 += 64) {
        const int row = t >> 3, col = (t & 7) * 8;
        #pragma unroll
        for (int r = 0; r < 4; r++) {
            const float* p = wproj + (size_t)(o0 + row + r * 32) * 256 + k0 + col;
            f32x4 v0 = *(const f32x4*)p;
            f32x4 v1 = *(const f32x4*)(p + 4);
            u16x8 o8 = { bfc(v0[0]), bfc(v0[1]), bfc(v0[2]), bfc(v0[3]),
                         bfc(v1[0]), bfc(v1[1]), bfc(v1[2]), bfc(v1[3]) };
            *(u16x8*)(&Wt[(row + r * 32) * 72 + col]) = o8;
            u16x8 a = *(const u16x8*)(att + (((size_t)b) * 4096 + n0 + row + r * 32) * 256 + k0 + col);
            *(u16x8*)(&Bt[(row + r * 32) * 72 + col]) = a;
        }
        __syncthreads();
        #pragma unroll
        for (int kk = 0; kk < 2; kk++) {
            bf16x8 af[4], bfr[4];
            #pragma unroll
            for (int i = 0; i < 4; i++)
                af[i] = *(const bf16x8*)(&Wt[(wr * 64 + i * 16 + l15) * 72 + kk * 32 + g * 8]);
            #pragma unroll
            for (int j = 0; j < 4; j++)
                bfr[j] = *(const bf16x8*)(&Bt[(wc * 64 + j * 16 + l15) * 72 + kk * 32 + g * 8]);
            #pragma unroll
            for (int i = 0; i < 4; i++)
                #pragma unroll
                for (int j = 0; j < 4; j++)
                    acc[i][j] = mfma16(af[i], bfr[j], acc[i][j]);
        }
        __syncthreads();
    }

    #pragma unroll
    for (int i = 0; i < 4; i++) {
        const int o = o0 + wr * 64 + i * 16 + g * 4;
        #pragma unroll
        for (int j = 0; j < 4; j++) {
            const int n = n0 + wc * 64 + j * 16 + l15;
            f32x4 a = acc[i][j];
            #pragma unroll
            for (int r = 0; r < 4; r++)
                proj[((size_t)(b * 256 + o + r)) * 4096 + n] = a[r];
        }
    }
}

// ---------------------------------------------------------------------------
// Kernel 4: BN stats.  One block per channel o: mean/rstd over (b,n) = 16384.
// ---------------------------------------------------------------------------
__global__ __launch_bounds__(256) void bn_stats(const float* __restrict__ proj,
                                                float* __restrict__ stats) {
    const int o = blockIdx.x, t = threadIdx.x;
    const int lane = t & 63, w = t >> 6;
    float s = 0.f, sq = 0.f;
    for (int i = 0; i < 64; i++) {
        const int idx = t + i * 256;
        const int bb = idx >> 12, n = idx & 4095;
        const float v = proj[((size_t)(bb * 256 + o)) * 4096 + n];
        s += v; sq += v * v;
    }
    #pragma unroll
    for (int m = 1; m < 64; m <<= 1) {
        s  += __shfl_xor(s, m, 64);
        sq += __shfl_xor(sq, m, 64);
    }
    __shared__ float red[8];
    if (lane == 0) { red[w] = s; red[4 + w] = sq; }
    __syncthreads();
    if (t == 0) {
        const float S = red[0] + red[1] + red[2] + red[3];
        const float Q = red[4] + red[5] + red[6] + red[7];
        const float mean = S * (1.f / 16384.f);
        const float var = Q * (1.f / 16384.f) - mean * mean;
        stats[o] = mean;
        stats[256 + o] = rsqrtf(var + 1e-5f);
    }
}

// ---------------------------------------------------------------------------
// Kernel 5: BN apply + gamma/beta + concat skip.  All f32 I/O.
// ---------------------------------------------------------------------------
__global__ __launch_bounds__(256) void bn_apply(
    const float* __restrict__ proj, const float* __restrict__ stats,
    const float* __restrict__ gamma, const float* __restrict__ beta,
    const float* __restrict__ x, float* __restrict__ out) {
    const size_t idx8 = ((size_t)blockIdx.x * 256 + threadIdx.x) * 8;
    const int n  = (int)(idx8 & 4095);
    const int ch = (int)((idx8 >> 12) & 511);
    const int b  = (int)(idx8 >> 21);
    if (ch < 256) {
        const float mean = stats[ch], rstd = stats[256 + ch];
        const float sc = gamma[ch] * rstd;
        const float sh = beta[ch] - mean * sc;
        const float* p = proj + (((size_t)(b * 256 + ch)) << 12) + n;
        f32x4 v0 = *(const f32x4*)p;
        f32x4 v1 = *(const f32x4*)(p + 4);
        f32x4 o0, o1;
        #pragma unroll
        for (int j = 0; j < 4; j++) { o0[j] = v0[j] * sc + sh; o1[j] = v1[j] * sc + sh; }
        *(f32x4*)(out + idx8) = o0;
        *(f32x4*)(out + idx8 + 4) = o1;
    } else {
        *(f32x4*)(out + idx8)     = *(const f32x4*)(x + idx8);
        *(f32x4*)(out + idx8 + 4) = *(const f32x4*)(x + idx8 + 4);
    }
}

// ---------------------------------------------------------------------------
extern "C" void kernel_launch(void* const* d_in, const int* in_sizes, int n_in,
                              void* d_out, int out_size, void* d_ws, size_t ws_size,
                              hipStream_t stream) {
    const float* x     = (const float*)d_in[0];
    const float* wqkv  = (const float*)d_in[1];
    const float* wproj = (const float*)d_in[2];
    const float* gamma = (const float*)d_in[3];
    const float* beta  = (const float*)d_in[4];
    float* out = (float*)d_out;

    char* ws = (char*)d_ws;
    unsigned short* Qb  = (unsigned short*)(ws);                    // 8 MB
    unsigned short* Kb  = (unsigned short*)(ws + (8u  << 20));      // 8 MB
    unsigned short* Vb  = (unsigned short*)(ws + (16u << 20));      // 8 MB
    unsigned short* att = (unsigned short*)(ws + (24u << 20));      // 8 MB
    float*          proj = (float*)(ws + (32u << 20));              // 16 MB
    float*          stats = (float*)(ws + (48u << 20));             // 2 KB

    qkv_gemm <<<dim3(6, 32, 4), 256, 0, stream>>>(x, wqkv, Qb, Kb, Vb);
    flash_attn<<<dim3(32, 16),   512, 0, stream>>>(Qb, Kb, Vb, att);
    proj_gemm<<<dim3(2, 32, 4),  256, 0, stream>>>(att, wproj, proj);
    bn_stats <<<256,             256, 0, stream>>>(proj, stats);
    bn_apply <<<4096,            256, 0, stream>>>(proj, stats, gamma, beta, x, out);
}